// Round 9
// baseline (147.885 us; speedup 1.0000x reference)
//
#include <hip/hip_runtime.h>
#include <hip/hip_bf16.h>

typedef __bf16 bf16x8 __attribute__((ext_vector_type(8)));
typedef float f32x4 __attribute__((ext_vector_type(4)));

#define LOG2E 1.4426950408889634f
#define LAMBDA_INIT 0.3555090675909693f
#define CEXP 0.18033688011112042f   // 0.125 * LOG2E
#define MOFF 11.541560327111708f    // 8 * LOG2E  (fixed raw max = 64)

// ws layout (bytes):
//  q   : [0, 4.19M)        bf16 [16384][128]
//  k   : [4.19M, 8.39M)    bf16 [16384][128]
//  vT  : [8.39M, 12.58M)   bf16 [4][128][4096]
//  part: [12.58M, 46.66M)  2048 recs x 16640B  (l[64] f32 + O[64][128] bf16)
//  WT  : [46.66M, 47.45M)  bf16 [3][128][1024]
#define K_OFF   ((size_t)16384 * 128)
#define VT_OFF  ((size_t)2 * 16384 * 128)
#define PART_OFF_BYTES ((size_t)12582912)
#define WT_OFF_BYTES   ((size_t)46661632)
#define REC_FLOATS 4160  // 64 l + 4096 words of bf16 O

__device__ __forceinline__ unsigned short f2bf(float f) {
    __hip_bfloat16 h = __float2bfloat16(f);
    unsigned short u;
    __builtin_memcpy(&u, &h, 2);
    return u;
}
__device__ __forceinline__ float bf2f(unsigned short u) {
    unsigned int x = ((unsigned int)u) << 16;
    float f;
    __builtin_memcpy(&f, &x, 4);
    return f;
}
__device__ __forceinline__ unsigned int cvt_pk_bf16(float a, float b) {
    unsigned int r;
    asm volatile("v_cvt_pk_bf16_f32 %0, %1, %2" : "=v"(r) : "v"(a), "v"(b));
    return r;
}

// ---------------- W pre-transpose: [1024][128] f32 -> [128][1024] bf16 ----------------
__global__ __launch_bounds__(256) void prep_wt(
    const float* __restrict__ Wq, const float* __restrict__ Wk,
    const float* __restrict__ Wv, unsigned short* __restrict__ WT) {
    const int kt = blockIdx.x, nt = blockIdx.y, mat = blockIdx.z;
    const float* W = (mat == 0) ? Wq : (mat == 1) ? Wk : Wv;
    unsigned short* O = WT + (size_t)mat * 128 * 1024;
    __shared__ float tb[64][65];
    const int r = threadIdx.x >> 2, c4 = (threadIdx.x & 3) * 16;
    for (int j = 0; j < 4; ++j) {
        float4 v = *(const float4*)&W[(size_t)(kt * 64 + r) * 128 + nt * 64 + c4 + j * 4];
        tb[r][c4 + j * 4 + 0] = v.x;
        tb[r][c4 + j * 4 + 1] = v.y;
        tb[r][c4 + j * 4 + 2] = v.z;
        tb[r][c4 + j * 4 + 3] = v.w;
    }
    __syncthreads();
    unsigned short tmp[16];
    for (int j = 0; j < 16; ++j) tmp[j] = f2bf(tb[c4 + j][r]);
    *(uint4*)&O[(size_t)(nt * 64 + r) * 1024 + kt * 64 + c4] = *(uint4*)&tmp[0];
    *(uint4*)&O[(size_t)(nt * 64 + r) * 1024 + kt * 64 + c4 + 8] = *(uint4*)&tmp[8];
}

// ---------------- QKV projection ----------------
// grid (3, 128): mat varies FASTEST so the 3 mats' same-row blocks are
// co-resident -> x row-tile fetched from HBM once, L2/L3 hits for the others.
__global__ __launch_bounds__(256) void qkv_gemm(
    const float* __restrict__ x, const unsigned short* __restrict__ WT,
    unsigned short* __restrict__ qkv) {
    const int tid = threadIdx.x;
    const int l = tid & 63, wid = tid >> 6;
    const int g = l >> 4, i16 = l & 15;
    const int row0 = blockIdx.y * 128;
    const int mat = blockIdx.x;
    const unsigned short* Wt = WT + (size_t)mat * 128 * 1024;

    __shared__ unsigned short smem[2][128][72];
    auto xs = smem[0];
    auto wt = smem[1];

    f32x4 acc[2][8];
    const f32x4 z4 = {0.f, 0.f, 0.f, 0.f};
    for (int a = 0; a < 2; ++a)
        for (int b = 0; b < 8; ++b) acc[a][b] = z4;

    for (int k0 = 0; k0 < 1024; k0 += 64) {
        __syncthreads();
        {
            const int c = (tid & 15) * 4;
            const int rbase = tid >> 4;
            #pragma unroll
            for (int it = 0; it < 8; ++it) {
                int r = rbase + it * 16;
                const float4 v = *(const float4*)&x[(size_t)(row0 + r) * 1024 + k0 + c];
                uint2 pk;
                pk.x = cvt_pk_bf16(v.x, v.y);
                pk.y = cvt_pk_bf16(v.z, v.w);
                *(uint2*)&xs[r][c] = pk;
            }
        }
        {
            #pragma unroll
            for (int it = 0; it < 4; ++it) {
                int lin = it * 256 + tid;
                int n = lin >> 3, k8 = (lin & 7) * 8;
                *(uint4*)&wt[n][k8] = *(const uint4*)&Wt[(size_t)n * 1024 + k0 + k8];
            }
        }
        __syncthreads();

        bf16x8 af[2][2];
        for (int rb = 0; rb < 2; ++rb)
            for (int c = 0; c < 2; ++c)
                af[rb][c] = *(const bf16x8*)&xs[wid * 32 + rb * 16 + i16][c * 32 + 8 * g];
        for (int nb = 0; nb < 8; ++nb) {
            bf16x8 b0 = *(const bf16x8*)&wt[nb * 16 + i16][8 * g];
            bf16x8 b1 = *(const bf16x8*)&wt[nb * 16 + i16][32 + 8 * g];
            for (int rb = 0; rb < 2; ++rb) {
                acc[rb][nb] = __builtin_amdgcn_mfma_f32_16x16x32_bf16(af[rb][0], b0, acc[rb][nb], 0, 0, 0);
                acc[rb][nb] = __builtin_amdgcn_mfma_f32_16x16x32_bf16(af[rb][1], b1, acc[rb][nb], 0, 0, 0);
            }
        }
    }

    __syncthreads();
    unsigned short(*ts)[136] = (unsigned short(*)[136]) & smem[0][0][0];
    for (int rb = 0; rb < 2; ++rb)
        for (int nb = 0; nb < 8; ++nb)
            for (int r = 0; r < 4; ++r)
                ts[wid * 32 + rb * 16 + g * 4 + r][nb * 16 + i16] = f2bf(acc[rb][nb][r]);
    __syncthreads();
    if (mat < 2) {
        unsigned short* outp = qkv + (size_t)mat * 16384 * 128 + (size_t)row0 * 128;
        #pragma unroll
        for (int it = 0; it < 8; ++it) {
            int tr = it * 16 + (tid >> 4), dv0 = (tid & 15) * 8;
            *(uint4*)&outp[tr * 128 + dv0] = *(const uint4*)&ts[tr][dv0];
        }
    } else {
        unsigned short* vtb = qkv + VT_OFF + (size_t)(row0 >> 12) * 128 * 4096 + (size_t)(row0 & 4095);
        const int dv = tid >> 1, half = tid & 1;
        #pragma unroll
        for (int blk = 0; blk < 8; ++blk) {
            unsigned short tmp[8];
            #pragma unroll
            for (int j = 0; j < 8; ++j) tmp[j] = ts[half * 64 + blk * 8 + j][dv];
            *(uint4*)&vtb[(size_t)dv * 4096 + half * 64 + blk * 8] = *(uint4*)tmp;
        }
    }
}

// ---------------- Differential causal flash attention ----------------
// grid (32, 4, 8): z = c*2+branch. Block (bx,b,c,branch): chunk c of rows
// t=bx and t=63-bx, one branch. 4 waves x 16 q-rows.
// FRAG-LINEAR LDS: K/V/P stored in exact per-MFMA lane order -> every
// fragment read is base + lane*16B: sequential, zero bank conflicts.
//   ksf[(cb*2+cc)*64 + l] <-> K[cb*16+(l&15)][cc*32+8*(l>>4) ..+8]
//   vtf[(nb*2+cc)*64 + l] <-> V^T[nb*16+(l&15)][cc*32+8*(l>>4) ..+8]
//   psf[w][ccp][l]        <-> P[q=(l&15)][ccp*32+8*(l>>4) ..+8]
// 32.0 KB LDS -> 5 blocks/CU (160KB exactly).
__global__ __launch_bounds__(256) void diff_attn_pair(
    const unsigned short* __restrict__ q, const unsigned short* __restrict__ kk_,
    const unsigned short* __restrict__ vvt,
    float* __restrict__ part) {
    const int bx = blockIdx.x, b = blockIdx.y;
    const int c = blockIdx.z >> 1, branch = blockIdx.z & 1;

    const int tid = threadIdx.x;
    const int l = tid & 63, w = tid >> 6;
    const int gq = l >> 4, i16 = l & 15;
    const float NEGINF = -__builtin_inff();

    __shared__ unsigned short ksf[4096];  //  8 KB: [4 cb][2 cc][64 l][8]
    __shared__ unsigned short vtf[8192];  // 16 KB: [8 nb][2 cc][64 l][8]
    __shared__ unsigned short psf[4096];  //  8 KB: [4 w][2 ccp][64 l][8]

    // staging constants (per thread)
    const int kgoff = (w * 16 + i16) * 128 + 8 * gq;   // + branch*64 in base
    const int kdst0 = ((w * 2 + 0) * 64 + l) * 8;
    const int kdst1 = ((w * 2 + 1) * 64 + l) * 8;
    const int vg0 = (w * 16 + i16) * 4096 + 8 * gq;        // nb=w,   cc=0
    const int vg2 = ((w + 4) * 16 + i16) * 4096 + 8 * gq;  // nb=w+4, cc=0
    const int vdst0 = ((w * 2 + 0) * 64 + l) * 8;          // nb=w  cc=0
    const int vdst1 = ((w * 2 + 1) * 64 + l) * 8;          // nb=w  cc=1
    const int vdst2 = (((w + 4) * 2 + 0) * 64 + l) * 8;
    const int vdst3 = (((w + 4) * 2 + 1) * 64 + l) * 8;
    // P write slots per cb
    int pdst[4];
    #pragma unroll
    for (int cb = 0; cb < 4; ++cb)
        pdst[cb] = ((w * 2 + (cb >> 1)) * 64 + ((cb & 1) * 2 + (gq >> 1)) * 16 + i16) * 8 + (gq & 1) * 4;
    const int prd0 = ((w * 2 + 0) * 64 + l) * 8;
    const int prd1 = ((w * 2 + 1) * 64 + l) * 8;

    const size_t bbase = (size_t)b * 4096;
    const size_t vbase = (size_t)b * 524288;
    const f32x4 z4 = {0.f, 0.f, 0.f, 0.f};
    uint4 kr0, kr1, vr0, vr1, vr2, vr3;

#define KV_LOAD(s_) do {                                                            \
        const unsigned short* kp = &kk_[(bbase + (size_t)(s_) * 64) * 128 + branch * 64]; \
        kr0 = *(const uint4*)&kp[kgoff];                                            \
        kr1 = *(const uint4*)&kp[kgoff + 32];                                       \
        const unsigned short* vp = &vvt[vbase + (size_t)(s_) * 64];                 \
        vr0 = *(const uint4*)&vp[vg0];                                              \
        vr1 = *(const uint4*)&vp[vg0 + 32];                                         \
        vr2 = *(const uint4*)&vp[vg2];                                              \
        vr3 = *(const uint4*)&vp[vg2 + 32];                                         \
    } while (0)

#define KV_STORE() do {                                                             \
        *(uint4*)&ksf[kdst0] = kr0;                                                 \
        *(uint4*)&ksf[kdst1] = kr1;                                                 \
        *(uint4*)&vtf[vdst0] = vr0;                                                 \
        *(uint4*)&vtf[vdst1] = vr1;                                                 \
        *(uint4*)&vtf[vdst2] = vr2;                                                 \
        *(uint4*)&vtf[vdst3] = vr3;                                                 \
    } while (0)

    #pragma unroll 1
    for (int seg = 0; seg < 2; ++seg) {
        const int t = seg ? (63 - bx) : bx;
        const int n = t + 1;
        const int s0 = (c * n) >> 2, smax = ((c + 1) * n) >> 2;

        float* rec = part + ((((size_t)b * 64 + t) * 4 + c) * 2 + branch) * REC_FLOATS;
        if (s0 >= smax) {  // empty chunk: zero this branch's record
            unsigned int* pz = (unsigned int*)rec;
            for (int i = tid; i < REC_FLOATS; i += 256) pz[i] = 0u;
            continue;
        }

        bf16x8 qf[2];
        for (int cc = 0; cc < 2; ++cc)
            qf[cc] = *(const bf16x8*)&q[(bbase + t * 64 + w * 16 + i16) * 128 + branch * 64 + cc * 32 + 8 * gq];

        float lsum = 0.f;
        f32x4 acc_o[8];
        for (int nb = 0; nb < 8; ++nb) acc_o[nb] = z4;

        KV_LOAD(s0);
        #pragma unroll 1
        for (int s = s0; s < smax; ++s) {
            __syncthreads();
            KV_STORE();
            if (s + 1 < smax) KV_LOAD(s + 1);
            __syncthreads();

            // S^T = mfma(K, Q): lane holds S[kv=cb*16+gq*4+r][q=w*16+i16]
            f32x4 sc[4];
            for (int cb = 0; cb < 4; ++cb) sc[cb] = z4;
            __builtin_amdgcn_s_setprio(1);
            #pragma unroll
            for (int cb = 0; cb < 4; ++cb)
                for (int cc = 0; cc < 2; ++cc) {
                    bf16x8 kf = *(const bf16x8*)&ksf[((cb * 2 + cc) * 64 + l) * 8];
                    sc[cb] = __builtin_amdgcn_mfma_f32_16x16x32_bf16(kf, qf[cc], sc[cb], 0, 0, 0);
                }
            __builtin_amdgcn_s_setprio(0);
            if (s == t) {  // causal mask on diagonal tile
                int ql = w * 16 + i16;
                for (int cb = 0; cb < 4; ++cb)
                    for (int r = 0; r < 4; ++r)
                        if (cb * 16 + gq * 4 + r > ql) sc[cb][r] = NEGINF;
            }
            // p = exp2(s*CEXP - MOFF); fixed max, per-lane lsum
            #pragma unroll
            for (int cb = 0; cb < 4; ++cb)
                for (int r = 0; r < 4; ++r) {
                    float pv = exp2f(fmaf(sc[cb][r], CEXP, -MOFF));
                    sc[cb][r] = pv;
                    lsum += pv;
                }
            // pack -> frag-linear P slots (b64 writes)
            #pragma unroll
            for (int cb = 0; cb < 4; ++cb) {
                uint2 pw;
                pw.x = cvt_pk_bf16(sc[cb][0], sc[cb][1]);
                pw.y = cvt_pk_bf16(sc[cb][2], sc[cb][3]);
                *(uint2*)&psf[pdst[cb]] = pw;
            }
            asm volatile("s_waitcnt lgkmcnt(0)" ::: "memory");  // wave-local
            bf16x8 pa0 = *(const bf16x8*)&psf[prd0];
            bf16x8 pa1 = *(const bf16x8*)&psf[prd1];
            __builtin_amdgcn_s_setprio(1);
            #pragma unroll
            for (int nb = 0; nb < 8; ++nb) {
                bf16x8 vb0 = *(const bf16x8*)&vtf[((nb * 2 + 0) * 64 + l) * 8];
                acc_o[nb] = __builtin_amdgcn_mfma_f32_16x16x32_bf16(pa0, vb0, acc_o[nb], 0, 0, 0);
                bf16x8 vb1 = *(const bf16x8*)&vtf[((nb * 2 + 1) * 64 + l) * 8];
                acc_o[nb] = __builtin_amdgcn_mfma_f32_16x16x32_bf16(pa1, vb1, acc_o[nb], 0, 0, 0);
            }
            __builtin_amdgcn_s_setprio(0);
        }

        // flush
        lsum += __shfl_xor(lsum, 16);
        lsum += __shfl_xor(lsum, 32);
        unsigned short* Orec = (unsigned short*)(rec + 64);
        if (gq == 0) rec[w * 16 + i16] = lsum;
        for (int nb = 0; nb < 8; ++nb)
            for (int r = 0; r < 4; ++r) {
                int row = w * 16 + gq * 4 + r;
                Orec[row * 128 + nb * 16 + i16] = f2bf(acc_o[nb][r]);
            }
    }
#undef KV_LOAD
#undef KV_STORE
}

// ---------------- combine: sum 4 chunks per branch, normalize, o1 - lam*o2 ----------------
__global__ __launch_bounds__(256) void diff_combine(
    const float* __restrict__ part,
    const float* __restrict__ lq1, const float* __restrict__ lq2,
    const float* __restrict__ lk1, const float* __restrict__ lk2,
    float* __restrict__ out) {
    const int t = blockIdx.x, b = blockIdx.y;
    const int tid = threadIdx.x;
    __shared__ float sl[2][64];
    __shared__ float s_lam;

    const float* recbase = part + (((size_t)b * 64 + t) * 4) * 2 * REC_FLOATS;

    if (tid < 64) {
        float s1 = lq1[tid] * lk1[tid];
        float s2 = lq2[tid] * lk2[tid];
        for (int off = 32; off > 0; off >>= 1) {
            s1 += __shfl_xor(s1, off);
            s2 += __shfl_xor(s2, off);
        }
        if (tid == 0) s_lam = expf(s1) - expf(s2) + LAMBDA_INIT;
    }
    if (tid < 128) {
        int r = tid & 63, br = tid >> 6;
        float acc = 0.f;
        for (int c = 0; c < 4; ++c) acc += recbase[(c * 2 + br) * REC_FLOATS + r];
        sl[br][r] = acc;
    }
    __syncthreads();
    const float lam = s_lam;

    float* op = out + ((size_t)b * 4096 + (size_t)t * 64) * 128;
    for (int grp = 0; grp < 4; ++grp) {
        int gid = grp * 256 + tid;
        int e = gid * 8;
        int row = e >> 7;
        float o1[8] = {0, 0, 0, 0, 0, 0, 0, 0}, o2[8] = {0, 0, 0, 0, 0, 0, 0, 0};
        #pragma unroll
        for (int c = 0; c < 4; ++c) {
            const unsigned short* O0 = (const unsigned short*)(recbase + (c * 2 + 0) * REC_FLOATS + 64);
            const unsigned short* O1 = (const unsigned short*)(recbase + (c * 2 + 1) * REC_FLOATS + 64);
            uint4 u0 = *(const uint4*)&O0[e];
            uint4 u1 = *(const uint4*)&O1[e];
            const unsigned short* e0 = (const unsigned short*)&u0;
            const unsigned short* e1 = (const unsigned short*)&u1;
            #pragma unroll
            for (int j = 0; j < 8; ++j) {
                o1[j] += bf2f(e0[j]);
                o2[j] += bf2f(e1[j]);
            }
        }
        float l1inv = 1.0f / sl[0][row], l2inv = 1.0f / sl[1][row];
        float res[8];
        #pragma unroll
        for (int j = 0; j < 8; ++j) res[j] = o1[j] * l1inv - lam * o2[j] * l2inv;
        *(float4*)&op[e] = *(float4*)&res[0];
        *(float4*)&op[e + 4] = *(float4*)&res[4];
    }
}

extern "C" void kernel_launch(void* const* d_in, const int* in_sizes, int n_in,
                              void* d_out, int out_size, void* d_ws, size_t ws_size,
                              hipStream_t stream) {
    const float* x   = (const float*)d_in[0];
    const float* Wq  = (const float*)d_in[1];
    const float* Wk  = (const float*)d_in[2];
    const float* Wv  = (const float*)d_in[3];
    const float* lq1 = (const float*)d_in[4];
    const float* lq2 = (const float*)d_in[5];
    const float* lk1 = (const float*)d_in[6];
    const float* lk2 = (const float*)d_in[7];
    float* out = (float*)d_out;
    unsigned short* qkv = (unsigned short*)d_ws;
    float* part = (float*)((char*)d_ws + PART_OFF_BYTES);
    unsigned short* WT = (unsigned short*)((char*)d_ws + WT_OFF_BYTES);

    prep_wt<<<dim3(16, 2, 3), 256, 0, stream>>>(Wq, Wk, Wv, WT);
    qkv_gemm<<<dim3(3, 128), 256, 0, stream>>>(x, WT, qkv);

    const unsigned short* qb = qkv;
    const unsigned short* kb = qkv + K_OFF;
    const unsigned short* vtb = qkv + VT_OFF;
    diff_attn_pair<<<dim3(32, 4, 8), 256, 0, stream>>>(qb, kb, vtb, part);
    diff_combine<<<dim3(64, 4), 256, 0, stream>>>(part, lq1, lq2, lk1, lk2, out);
}

// Round 10
// 113.008 us; speedup vs baseline: 1.3086x; 1.3086x over previous
//
#include <hip/hip_runtime.h>
#include <hip/hip_bf16.h>

typedef __bf16 bf16x8 __attribute__((ext_vector_type(8)));
typedef float f32x4 __attribute__((ext_vector_type(4)));

#define LOG2E 1.4426950408889634f
#define LAMBDA_INIT 0.3555090675909693f
#define CEXP 0.18033688011112042f   // 0.125 * LOG2E
#define MOFF 11.541560327111708f    // 8 * LOG2E  (fixed raw max = 64)

// ws layout (bytes):
//  q   : [0, 4.19M)        bf16 [16384][128]
//  k   : [4.19M, 8.39M)    bf16 [16384][128]
//  vT  : [8.39M, 12.58M)   bf16 [4][128][4096]
//  part: [12.58M, 46.66M)  2048 recs x 16640B  (l[64] f32 + O[64][128] bf16)
//  WT  : [46.66M, 47.45M)  bf16 [3][128][1024]
#define K_OFF   ((size_t)16384 * 128)
#define VT_OFF  ((size_t)2 * 16384 * 128)
#define PART_OFF_BYTES ((size_t)12582912)
#define WT_OFF_BYTES   ((size_t)46661632)
#define REC_FLOATS 4160  // 64 l + 4096 words of bf16 O

__device__ __forceinline__ unsigned short f2bf(float f) {
    __hip_bfloat16 h = __float2bfloat16(f);
    unsigned short u;
    __builtin_memcpy(&u, &h, 2);
    return u;
}
__device__ __forceinline__ float bf2f(unsigned short u) {
    unsigned int x = ((unsigned int)u) << 16;
    float f;
    __builtin_memcpy(&f, &x, 4);
    return f;
}
__device__ __forceinline__ unsigned int cvt_pk_bf16(float a, float b) {
    unsigned int r;
    asm volatile("v_cvt_pk_bf16_f32 %0, %1, %2" : "=v"(r) : "v"(a), "v"(b));
    return r;
}

// ---------------- W pre-transpose: [1024][128] f32 -> [128][1024] bf16 ----------------
__global__ __launch_bounds__(256) void prep_wt(
    const float* __restrict__ Wq, const float* __restrict__ Wk,
    const float* __restrict__ Wv, unsigned short* __restrict__ WT) {
    const int kt = blockIdx.x, nt = blockIdx.y, mat = blockIdx.z;
    const float* W = (mat == 0) ? Wq : (mat == 1) ? Wk : Wv;
    unsigned short* O = WT + (size_t)mat * 128 * 1024;
    __shared__ float tb[64][65];
    const int r = threadIdx.x >> 2, c4 = (threadIdx.x & 3) * 16;
    for (int j = 0; j < 4; ++j) {
        float4 v = *(const float4*)&W[(size_t)(kt * 64 + r) * 128 + nt * 64 + c4 + j * 4];
        tb[r][c4 + j * 4 + 0] = v.x;
        tb[r][c4 + j * 4 + 1] = v.y;
        tb[r][c4 + j * 4 + 2] = v.z;
        tb[r][c4 + j * 4 + 3] = v.w;
    }
    __syncthreads();
    unsigned short tmp[16];
    for (int j = 0; j < 16; ++j) tmp[j] = f2bf(tb[c4 + j][r]);
    *(uint4*)&O[(size_t)(nt * 64 + r) * 1024 + kt * 64 + c4] = *(uint4*)&tmp[0];
    *(uint4*)&O[(size_t)(nt * 64 + r) * 1024 + kt * 64 + c4 + 8] = *(uint4*)&tmp[8];
}

// ---------------- QKV projection ----------------
// grid (128, 3): linear id = row + 128*mat -> the 3 mats' row-r blocks map to
// the SAME XCD (128 % 8 == 0): x tile lives in one L2 with 3 readers.
__global__ __launch_bounds__(256) void qkv_gemm(
    const float* __restrict__ x, const unsigned short* __restrict__ WT,
    unsigned short* __restrict__ qkv) {
    const int tid = threadIdx.x;
    const int l = tid & 63, wid = tid >> 6;
    const int g = l >> 4, i16 = l & 15;
    const int row0 = blockIdx.x * 128;
    const int mat = blockIdx.y;
    const unsigned short* Wt = WT + (size_t)mat * 128 * 1024;

    __shared__ unsigned short smem[2][128][72];
    auto xs = smem[0];
    auto wt = smem[1];

    f32x4 acc[2][8];
    const f32x4 z4 = {0.f, 0.f, 0.f, 0.f};
    for (int a = 0; a < 2; ++a)
        for (int b = 0; b < 8; ++b) acc[a][b] = z4;

    for (int k0 = 0; k0 < 1024; k0 += 64) {
        __syncthreads();
        {   // stage x tile (128 x 64) f32 -> bf16
            const int c = (tid & 15) * 4;
            const int rbase = tid >> 4;
            #pragma unroll
            for (int it = 0; it < 8; ++it) {
                int r = rbase + it * 16;
                const float4 v = *(const float4*)&x[(size_t)(row0 + r) * 1024 + k0 + c];
                ushort4 pk = make_ushort4(f2bf(v.x), f2bf(v.y), f2bf(v.z), f2bf(v.w));
                *(ushort4*)&xs[r][c] = pk;
            }
        }
        {   // stage W^T tile (128 n x 64 k) bf16 vectorized
            #pragma unroll
            for (int it = 0; it < 4; ++it) {
                int lin = it * 256 + tid;
                int n = lin >> 3, k8 = (lin & 7) * 8;
                *(uint4*)&wt[n][k8] = *(const uint4*)&Wt[(size_t)n * 1024 + k0 + k8];
            }
        }
        __syncthreads();

        bf16x8 af[2][2];
        for (int rb = 0; rb < 2; ++rb)
            for (int c = 0; c < 2; ++c)
                af[rb][c] = *(const bf16x8*)&xs[wid * 32 + rb * 16 + i16][c * 32 + 8 * g];
        for (int nb = 0; nb < 8; ++nb) {
            bf16x8 b0 = *(const bf16x8*)&wt[nb * 16 + i16][8 * g];
            bf16x8 b1 = *(const bf16x8*)&wt[nb * 16 + i16][32 + 8 * g];
            for (int rb = 0; rb < 2; ++rb) {
                acc[rb][nb] = __builtin_amdgcn_mfma_f32_16x16x32_bf16(af[rb][0], b0, acc[rb][nb], 0, 0, 0);
                acc[rb][nb] = __builtin_amdgcn_mfma_f32_16x16x32_bf16(af[rb][1], b1, acc[rb][nb], 0, 0, 0);
            }
        }
    }

    __syncthreads();
    unsigned short(*ts)[136] = (unsigned short(*)[136]) & smem[0][0][0];
    for (int rb = 0; rb < 2; ++rb)
        for (int nb = 0; nb < 8; ++nb)
            for (int r = 0; r < 4; ++r)
                ts[wid * 32 + rb * 16 + g * 4 + r][nb * 16 + i16] = f2bf(acc[rb][nb][r]);
    __syncthreads();
    if (mat < 2) {
        unsigned short* outp = qkv + (size_t)mat * 16384 * 128 + (size_t)row0 * 128;
        #pragma unroll
        for (int it = 0; it < 8; ++it) {
            int tr = it * 16 + (tid >> 4), dv0 = (tid & 15) * 8;
            *(uint4*)&outp[tr * 128 + dv0] = *(const uint4*)&ts[tr][dv0];
        }
    } else {
        unsigned short* vtb = qkv + VT_OFF + (size_t)(row0 >> 12) * 128 * 4096 + (size_t)(row0 & 4095);
        const int dv = tid >> 1, half = tid & 1;
        #pragma unroll
        for (int blk = 0; blk < 8; ++blk) {
            unsigned short tmp[8];
            #pragma unroll
            for (int j = 0; j < 8; ++j) tmp[j] = ts[half * 64 + blk * 8 + j][dv];
            *(uint4*)&vtb[(size_t)dv * 4096 + half * 64 + blk * 8] = *(uint4*)tmp;
        }
    }
}

// ---------------- Differential causal flash attention ----------------
// grid (32, 4, 8): z = c*2+branch. Block (bx,b,c,branch): chunk c of rows
// t=bx and t=63-bx, one branch. 4 waves x 16 q-rows.
// FRAG-LINEAR LDS: K/V/P stored in exact per-MFMA lane order -> every
// fragment read is base + lane*16B: sequential, zero bank conflicts.
//   ksf[(cb*2+cc)*64 + l] <-> K[cb*16+(l&15)][cc*32+8*(l>>4) ..+8]
//   vtf[(nb*2+cc)*64 + l] <-> V^T[nb*16+(l&15)][cc*32+8*(l>>4) ..+8]
//   psf[w][ccp][l]        <-> P[q=(l&15)][ccp*32+8*(l>>4) ..+8]
// 32.0 KB LDS -> 5 blocks/CU (160KB exactly).
__global__ __launch_bounds__(256) void diff_attn_pair(
    const unsigned short* __restrict__ q, const unsigned short* __restrict__ kk_,
    const unsigned short* __restrict__ vvt,
    float* __restrict__ part) {
    const int bx = blockIdx.x, b = blockIdx.y;
    const int c = blockIdx.z >> 1, branch = blockIdx.z & 1;

    const int tid = threadIdx.x;
    const int l = tid & 63, w = tid >> 6;
    const int gq = l >> 4, i16 = l & 15;
    const float NEGINF = -__builtin_inff();

    __shared__ unsigned short ksf[4096];  //  8 KB: [4 cb][2 cc][64 l][8]
    __shared__ unsigned short vtf[8192];  // 16 KB: [8 nb][2 cc][64 l][8]
    __shared__ unsigned short psf[4096];  //  8 KB: [4 w][2 ccp][64 l][8]

    // staging constants (per thread)
    const int kgoff = (w * 16 + i16) * 128 + 8 * gq;   // + branch*64 in base
    const int kdst0 = ((w * 2 + 0) * 64 + l) * 8;
    const int kdst1 = ((w * 2 + 1) * 64 + l) * 8;
    const int vg0 = (w * 16 + i16) * 4096 + 8 * gq;        // nb=w,   cc=0
    const int vg2 = ((w + 4) * 16 + i16) * 4096 + 8 * gq;  // nb=w+4, cc=0
    const int vdst0 = ((w * 2 + 0) * 64 + l) * 8;          // nb=w  cc=0
    const int vdst1 = ((w * 2 + 1) * 64 + l) * 8;          // nb=w  cc=1
    const int vdst2 = (((w + 4) * 2 + 0) * 64 + l) * 8;
    const int vdst3 = (((w + 4) * 2 + 1) * 64 + l) * 8;
    // P write slots per cb
    int pdst[4];
    #pragma unroll
    for (int cb = 0; cb < 4; ++cb)
        pdst[cb] = ((w * 2 + (cb >> 1)) * 64 + ((cb & 1) * 2 + (gq >> 1)) * 16 + i16) * 8 + (gq & 1) * 4;
    const int prd0 = ((w * 2 + 0) * 64 + l) * 8;
    const int prd1 = ((w * 2 + 1) * 64 + l) * 8;

    const size_t bbase = (size_t)b * 4096;
    const size_t vbase = (size_t)b * 524288;
    const f32x4 z4 = {0.f, 0.f, 0.f, 0.f};
    uint4 kr0, kr1, vr0, vr1, vr2, vr3;

#define KV_LOAD(s_) do {                                                            \
        const unsigned short* kp = &kk_[(bbase + (size_t)(s_) * 64) * 128 + branch * 64]; \
        kr0 = *(const uint4*)&kp[kgoff];                                            \
        kr1 = *(const uint4*)&kp[kgoff + 32];                                       \
        const unsigned short* vp = &vvt[vbase + (size_t)(s_) * 64];                 \
        vr0 = *(const uint4*)&vp[vg0];                                              \
        vr1 = *(const uint4*)&vp[vg0 + 32];                                         \
        vr2 = *(const uint4*)&vp[vg2];                                              \
        vr3 = *(const uint4*)&vp[vg2 + 32];                                         \
    } while (0)

#define KV_STORE() do {                                                             \
        *(uint4*)&ksf[kdst0] = kr0;                                                 \
        *(uint4*)&ksf[kdst1] = kr1;                                                 \
        *(uint4*)&vtf[vdst0] = vr0;                                                 \
        *(uint4*)&vtf[vdst1] = vr1;                                                 \
        *(uint4*)&vtf[vdst2] = vr2;                                                 \
        *(uint4*)&vtf[vdst3] = vr3;                                                 \
    } while (0)

    #pragma unroll 1
    for (int seg = 0; seg < 2; ++seg) {
        const int t = seg ? (63 - bx) : bx;
        const int n = t + 1;
        const int s0 = (c * n) >> 2, smax = ((c + 1) * n) >> 2;

        float* rec = part + ((((size_t)b * 64 + t) * 4 + c) * 2 + branch) * REC_FLOATS;
        if (s0 >= smax) {  // empty chunk: zero this branch's record
            unsigned int* pz = (unsigned int*)rec;
            for (int i = tid; i < REC_FLOATS; i += 256) pz[i] = 0u;
            continue;
        }

        bf16x8 qf[2];
        for (int cc = 0; cc < 2; ++cc)
            qf[cc] = *(const bf16x8*)&q[(bbase + t * 64 + w * 16 + i16) * 128 + branch * 64 + cc * 32 + 8 * gq];

        float lsum = 0.f;
        f32x4 acc_o[8];
        for (int nb = 0; nb < 8; ++nb) acc_o[nb] = z4;

        KV_LOAD(s0);
        #pragma unroll 1
        for (int s = s0; s < smax; ++s) {
            __syncthreads();
            KV_STORE();
            if (s + 1 < smax) KV_LOAD(s + 1);
            __syncthreads();

            // S^T = mfma(K, Q): lane holds S[kv=cb*16+gq*4+r][q=w*16+i16]
            f32x4 sc[4];
            for (int cb = 0; cb < 4; ++cb) sc[cb] = z4;
            __builtin_amdgcn_s_setprio(1);
            #pragma unroll
            for (int cb = 0; cb < 4; ++cb)
                for (int cc = 0; cc < 2; ++cc) {
                    bf16x8 kf = *(const bf16x8*)&ksf[((cb * 2 + cc) * 64 + l) * 8];
                    sc[cb] = __builtin_amdgcn_mfma_f32_16x16x32_bf16(kf, qf[cc], sc[cb], 0, 0, 0);
                }
            __builtin_amdgcn_s_setprio(0);
            if (s == t) {  // causal mask on diagonal tile
                int ql = w * 16 + i16;
                for (int cb = 0; cb < 4; ++cb)
                    for (int r = 0; r < 4; ++r)
                        if (cb * 16 + gq * 4 + r > ql) sc[cb][r] = NEGINF;
            }
            // p = exp2(s*CEXP - MOFF); fixed max, per-lane lsum
            #pragma unroll
            for (int cb = 0; cb < 4; ++cb)
                for (int r = 0; r < 4; ++r) {
                    float pv = exp2f(fmaf(sc[cb][r], CEXP, -MOFF));
                    sc[cb][r] = pv;
                    lsum += pv;
                }
            // pack -> frag-linear P slots (b64 writes)
            #pragma unroll
            for (int cb = 0; cb < 4; ++cb) {
                uint2 pw;
                pw.x = cvt_pk_bf16(sc[cb][0], sc[cb][1]);
                pw.y = cvt_pk_bf16(sc[cb][2], sc[cb][3]);
                *(uint2*)&psf[pdst[cb]] = pw;
            }
            asm volatile("s_waitcnt lgkmcnt(0)" ::: "memory");  // wave-local
            bf16x8 pa0 = *(const bf16x8*)&psf[prd0];
            bf16x8 pa1 = *(const bf16x8*)&psf[prd1];
            __builtin_amdgcn_s_setprio(1);
            #pragma unroll
            for (int nb = 0; nb < 8; ++nb) {
                bf16x8 vb0 = *(const bf16x8*)&vtf[((nb * 2 + 0) * 64 + l) * 8];
                acc_o[nb] = __builtin_amdgcn_mfma_f32_16x16x32_bf16(pa0, vb0, acc_o[nb], 0, 0, 0);
                bf16x8 vb1 = *(const bf16x8*)&vtf[((nb * 2 + 1) * 64 + l) * 8];
                acc_o[nb] = __builtin_amdgcn_mfma_f32_16x16x32_bf16(pa1, vb1, acc_o[nb], 0, 0, 0);
            }
            __builtin_amdgcn_s_setprio(0);
        }

        // flush
        lsum += __shfl_xor(lsum, 16);
        lsum += __shfl_xor(lsum, 32);
        unsigned short* Orec = (unsigned short*)(rec + 64);
        if (gq == 0) rec[w * 16 + i16] = lsum;
        for (int nb = 0; nb < 8; ++nb)
            for (int r = 0; r < 4; ++r) {
                int row = w * 16 + gq * 4 + r;
                Orec[row * 128 + nb * 16 + i16] = f2bf(acc_o[nb][r]);
            }
    }
#undef KV_LOAD
#undef KV_STORE
}

// ---------------- combine: sum 4 chunks per branch, normalize, o1 - lam*o2 ----------------
__global__ __launch_bounds__(256) void diff_combine(
    const float* __restrict__ part,
    const float* __restrict__ lq1, const float* __restrict__ lq2,
    const float* __restrict__ lk1, const float* __restrict__ lk2,
    float* __restrict__ out) {
    const int t = blockIdx.x, b = blockIdx.y;
    const int tid = threadIdx.x;
    __shared__ float sl[2][64];
    __shared__ float s_lam;

    const float* recbase = part + (((size_t)b * 64 + t) * 4) * 2 * REC_FLOATS;

    if (tid < 64) {
        float s1 = lq1[tid] * lk1[tid];
        float s2 = lq2[tid] * lk2[tid];
        for (int off = 32; off > 0; off >>= 1) {
            s1 += __shfl_xor(s1, off);
            s2 += __shfl_xor(s2, off);
        }
        if (tid == 0) s_lam = expf(s1) - expf(s2) + LAMBDA_INIT;
    }
    if (tid < 128) {
        int r = tid & 63, br = tid >> 6;
        float acc = 0.f;
        for (int c = 0; c < 4; ++c) acc += recbase[(c * 2 + br) * REC_FLOATS + r];
        sl[br][r] = acc;
    }
    __syncthreads();
    const float lam = s_lam;

    float* op = out + ((size_t)b * 4096 + (size_t)t * 64) * 128;
    for (int grp = 0; grp < 4; ++grp) {
        int gid = grp * 256 + tid;
        int e = gid * 8;
        int row = e >> 7;
        float o1[8] = {0, 0, 0, 0, 0, 0, 0, 0}, o2[8] = {0, 0, 0, 0, 0, 0, 0, 0};
        #pragma unroll
        for (int c = 0; c < 4; ++c) {
            const unsigned short* O0 = (const unsigned short*)(recbase + (c * 2 + 0) * REC_FLOATS + 64);
            const unsigned short* O1 = (const unsigned short*)(recbase + (c * 2 + 1) * REC_FLOATS + 64);
            uint4 u0 = *(const uint4*)&O0[e];
            uint4 u1 = *(const uint4*)&O1[e];
            const unsigned short* e0 = (const unsigned short*)&u0;
            const unsigned short* e1 = (const unsigned short*)&u1;
            #pragma unroll
            for (int j = 0; j < 8; ++j) {
                o1[j] += bf2f(e0[j]);
                o2[j] += bf2f(e1[j]);
            }
        }
        float l1inv = 1.0f / sl[0][row], l2inv = 1.0f / sl[1][row];
        float res[8];
        #pragma unroll
        for (int j = 0; j < 8; ++j) res[j] = o1[j] * l1inv - lam * o2[j] * l2inv;
        *(float4*)&op[e] = *(float4*)&res[0];
        *(float4*)&op[e + 4] = *(float4*)&res[4];
    }
}

extern "C" void kernel_launch(void* const* d_in, const int* in_sizes, int n_in,
                              void* d_out, int out_size, void* d_ws, size_t ws_size,
                              hipStream_t stream) {
    const float* x   = (const float*)d_in[0];
    const float* Wq  = (const float*)d_in[1];
    const float* Wk  = (const float*)d_in[2];
    const float* Wv  = (const float*)d_in[3];
    const float* lq1 = (const float*)d_in[4];
    const float* lq2 = (const float*)d_in[5];
    const float* lk1 = (const float*)d_in[6];
    const float* lk2 = (const float*)d_in[7];
    float* out = (float*)d_out;
    unsigned short* qkv = (unsigned short*)d_ws;
    float* part = (float*)((char*)d_ws + PART_OFF_BYTES);
    unsigned short* WT = (unsigned short*)((char*)d_ws + WT_OFF_BYTES);

    prep_wt<<<dim3(16, 2, 3), 256, 0, stream>>>(Wq, Wk, Wv, WT);
    qkv_gemm<<<dim3(128, 3), 256, 0, stream>>>(x, WT, qkv);

    const unsigned short* qb = qkv;
    const unsigned short* kb = qkv + K_OFF;
    const unsigned short* vtb = qkv + VT_OFF;
    diff_attn_pair<<<dim3(32, 4, 8), 256, 0, stream>>>(qb, kb, vtb, part);
    diff_combine<<<dim3(64, 4), 256, 0, stream>>>(part, lq1, lq2, lk1, lk2, out);
}

// Round 11
// 102.795 us; speedup vs baseline: 1.4386x; 1.0994x over previous
//
#include <hip/hip_runtime.h>
#include <hip/hip_bf16.h>

typedef __bf16 bf16x8 __attribute__((ext_vector_type(8)));
typedef float f32x4 __attribute__((ext_vector_type(4)));

#define LOG2E 1.4426950408889634f
#define LAMBDA_INIT 0.3555090675909693f
#define CEXP 0.18033688011112042f   // 0.125 * LOG2E
#define MOFF 11.541560327111708f    // 8 * LOG2E  (fixed raw max = 64)

// ws layout (bytes):
//  q    : [0, 4.19M)       bf16 [16384][128] row-major
//  kimg : [4.19M, 8.39M)   bf16 [4][64][2][8 regions][64 slots][8]  (frag image)
//  vimg : [8.39M, 12.58M)  bf16 [4][64][16 regions][64 slots][8]    (frag image)
//  part : [12.58M, 46.66M) 2048 recs x 16640B (l[64] f32 + O[64][128] bf16)
//  WT   : [46.66M, 47.45M) bf16 [3][128][1024]
#define K_OFF   ((size_t)16384 * 128)
#define VT_OFF  ((size_t)2 * 16384 * 128)
#define PART_OFF_BYTES ((size_t)12582912)
#define WT_OFF_BYTES   ((size_t)46661632)
#define REC_FLOATS 4160  // 64 l + 4096 words of bf16 O

__device__ __forceinline__ unsigned short f2bf(float f) {
    __hip_bfloat16 h = __float2bfloat16(f);
    unsigned short u;
    __builtin_memcpy(&u, &h, 2);
    return u;
}
__device__ __forceinline__ float bf2f(unsigned short u) {
    unsigned int x = ((unsigned int)u) << 16;
    float f;
    __builtin_memcpy(&f, &x, 4);
    return f;
}
__device__ __forceinline__ unsigned int cvt_pk_bf16(float a, float b) {
    unsigned int r;
    asm volatile("v_cvt_pk_bf16_f32 %0, %1, %2" : "=v"(r) : "v"(a), "v"(b));
    return r;
}

// ---------------- W pre-transpose: [1024][128] f32 -> [128][1024] bf16 ----------------
__global__ __launch_bounds__(256) void prep_wt(
    const float* __restrict__ Wq, const float* __restrict__ Wk,
    const float* __restrict__ Wv, unsigned short* __restrict__ WT) {
    const int kt = blockIdx.x, nt = blockIdx.y, mat = blockIdx.z;
    const float* W = (mat == 0) ? Wq : (mat == 1) ? Wk : Wv;
    unsigned short* O = WT + (size_t)mat * 128 * 1024;
    __shared__ float tb[64][65];
    const int r = threadIdx.x >> 2, c4 = (threadIdx.x & 3) * 16;
    for (int j = 0; j < 4; ++j) {
        float4 v = *(const float4*)&W[(size_t)(kt * 64 + r) * 128 + nt * 64 + c4 + j * 4];
        tb[r][c4 + j * 4 + 0] = v.x;
        tb[r][c4 + j * 4 + 1] = v.y;
        tb[r][c4 + j * 4 + 2] = v.z;
        tb[r][c4 + j * 4 + 3] = v.w;
    }
    __syncthreads();
    unsigned short tmp[16];
    for (int j = 0; j < 16; ++j) tmp[j] = f2bf(tb[c4 + j][r]);
    *(uint4*)&O[(size_t)(nt * 64 + r) * 1024 + kt * 64 + c4] = *(uint4*)&tmp[0];
    *(uint4*)&O[(size_t)(nt * 64 + r) * 1024 + kt * 64 + c4 + 8] = *(uint4*)&tmp[8];
}

// ---------------- QKV projection ----------------
// grid (128, 3): the 3 mats' row-r blocks map to the SAME XCD (128 % 8 == 0).
// K and V epilogues write the attention kernel's exact LDS frag image.
__global__ __launch_bounds__(256) void qkv_gemm(
    const float* __restrict__ x, const unsigned short* __restrict__ WT,
    unsigned short* __restrict__ qkv) {
    const int tid = threadIdx.x;
    const int l = tid & 63, wid = tid >> 6;
    const int g = l >> 4, i16 = l & 15;
    const int row0 = blockIdx.x * 128;
    const int mat = blockIdx.y;
    const unsigned short* Wt = WT + (size_t)mat * 128 * 1024;

    __shared__ unsigned short smem[2][128][72];
    auto xs = smem[0];
    auto wt = smem[1];

    f32x4 acc[2][8];
    const f32x4 z4 = {0.f, 0.f, 0.f, 0.f};
    for (int a = 0; a < 2; ++a)
        for (int b = 0; b < 8; ++b) acc[a][b] = z4;

    for (int k0 = 0; k0 < 1024; k0 += 64) {
        __syncthreads();
        {   // stage x tile (128 x 64) f32 -> bf16
            const int c = (tid & 15) * 4;
            const int rbase = tid >> 4;
            #pragma unroll
            for (int it = 0; it < 8; ++it) {
                int r = rbase + it * 16;
                const float4 v = *(const float4*)&x[(size_t)(row0 + r) * 1024 + k0 + c];
                ushort4 pk = make_ushort4(f2bf(v.x), f2bf(v.y), f2bf(v.z), f2bf(v.w));
                *(ushort4*)&xs[r][c] = pk;
            }
        }
        {   // stage W^T tile (128 n x 64 k) bf16 vectorized
            #pragma unroll
            for (int it = 0; it < 4; ++it) {
                int lin = it * 256 + tid;
                int n = lin >> 3, k8 = (lin & 7) * 8;
                *(uint4*)&wt[n][k8] = *(const uint4*)&Wt[(size_t)n * 1024 + k0 + k8];
            }
        }
        __syncthreads();

        bf16x8 af[2][2];
        for (int rb = 0; rb < 2; ++rb)
            for (int c = 0; c < 2; ++c)
                af[rb][c] = *(const bf16x8*)&xs[wid * 32 + rb * 16 + i16][c * 32 + 8 * g];
        for (int nb = 0; nb < 8; ++nb) {
            bf16x8 b0 = *(const bf16x8*)&wt[nb * 16 + i16][8 * g];
            bf16x8 b1 = *(const bf16x8*)&wt[nb * 16 + i16][32 + 8 * g];
            for (int rb = 0; rb < 2; ++rb) {
                acc[rb][nb] = __builtin_amdgcn_mfma_f32_16x16x32_bf16(af[rb][0], b0, acc[rb][nb], 0, 0, 0);
                acc[rb][nb] = __builtin_amdgcn_mfma_f32_16x16x32_bf16(af[rb][1], b1, acc[rb][nb], 0, 0, 0);
            }
        }
    }

    __syncthreads();
    unsigned short(*ts)[136] = (unsigned short(*)[136]) & smem[0][0][0];
    for (int rb = 0; rb < 2; ++rb)
        for (int nb = 0; nb < 8; ++nb)
            for (int r = 0; r < 4; ++r)
                ts[wid * 32 + rb * 16 + g * 4 + r][nb * 16 + i16] = f2bf(acc[rb][nb][r]);
    __syncthreads();

    const int bq = row0 >> 12;            // batch
    const int s0b = (row0 & 4095) >> 6;   // first kv-tile of this row block
    if (mat == 0) {
        unsigned short* outp = qkv + (size_t)row0 * 128;
        #pragma unroll
        for (int it = 0; it < 8; ++it) {
            int tr = it * 16 + (tid >> 4), dv0 = (tid & 15) * 8;
            *(uint4*)&outp[tr * 128 + dv0] = *(const uint4*)&ts[tr][dv0];
        }
    } else if (mat == 1) {
        // K frag image: [(b*64+s)*2+branch][region=cb*2+cc][slot=gq*16+i16][8]
        unsigned short* kimg = qkv + K_OFF;
        #pragma unroll
        for (int it = 0; it < 8; ++it) {
            int lin = it * 256 + tid;      // 0..2047 slots of the 2-tile image
            int tile = lin >> 10;
            int branch_ = (lin >> 9) & 1;
            int region = (lin >> 6) & 7;
            int slot = lin & 63;
            int row = tile * 64 + (region >> 1) * 16 + (slot & 15);
            int d = branch_ * 64 + (region & 1) * 32 + (slot >> 4) * 8;
            uint4 vv = *(const uint4*)&ts[row][d];
            size_t off = ((size_t)((bq * 64 + s0b + tile) * 2 + branch_) * 4096) + (region * 64 + slot) * 8;
            *(uint4*)&kimg[off] = vv;
        }
    } else {
        // V frag image: [b*64+s][region=nb*2+cc][slot=gq*16+i16][8], elem = kv&7
        unsigned short* vimg = qkv + VT_OFF;
        #pragma unroll
        for (int it = 0; it < 8; ++it) {
            int lin = it * 256 + tid;      // 0..2047 slots of the 2-tile image
            int tile = lin >> 10;
            int rem = lin & 1023;
            int region = rem >> 6;         // 0..15
            int slot = rem & 63;
            int dv = (region >> 1) * 16 + (slot & 15);
            int kv0 = (region & 1) * 32 + (slot >> 4) * 8;
            unsigned short tmp[8];
            #pragma unroll
            for (int e = 0; e < 8; ++e) tmp[e] = ts[tile * 64 + kv0 + e][dv];
            size_t off = ((size_t)(bq * 64 + s0b + tile) * 8192) + (region * 64 + slot) * 8;
            *(uint4*)&vimg[off] = *(uint4*)tmp;
        }
    }
}

// ---------------- Differential causal flash attention ----------------
// grid (32, 4, 8): z = c*2+branch. Block (bx,b,c,branch): chunk c of rows
// t=bx and t=63-bx, one branch. 4 waves x 16 q-rows.
// K/V pre-tiled in ws as the exact LDS frag image -> staging is a straight
// memcpy: 1KB-contiguous global loads per wave, lane-linear LDS writes,
// frag-linear LDS reads. Zero bank conflicts, minimal address VALU.
__global__ __launch_bounds__(256) void diff_attn_pair(
    const unsigned short* __restrict__ q, const unsigned short* __restrict__ kimg,
    const unsigned short* __restrict__ vimg,
    float* __restrict__ part) {
    const int bx = blockIdx.x, b = blockIdx.y;
    const int c = blockIdx.z >> 1, branch = blockIdx.z & 1;

    const int tid = threadIdx.x;
    const int l = tid & 63, w = tid >> 6;
    const int gq = l >> 4, i16 = l & 15;
    const float NEGINF = -__builtin_inff();

    __shared__ unsigned short ksf[4096];  //  8 KB: [8 region][64 slot][8]
    __shared__ unsigned short vtf[8192];  // 16 KB: [16 region][64 slot][8]
    __shared__ unsigned short psf[4096];  //  8 KB: [4 w][2 ccp][64 l][8]

    const int tid8 = tid * 8;
    // P write slots per cb
    int pdst[4];
    #pragma unroll
    for (int cb = 0; cb < 4; ++cb)
        pdst[cb] = ((w * 2 + (cb >> 1)) * 64 + ((cb & 1) * 2 + (gq >> 1)) * 16 + i16) * 8 + (gq & 1) * 4;
    const int prd0 = ((w * 2 + 0) * 64 + l) * 8;
    const int prd1 = ((w * 2 + 1) * 64 + l) * 8;

    const size_t bbase = (size_t)b * 4096;
    const unsigned short* kimg_b = kimg + (size_t)b * 524288;  // 64 tiles * 2 * 4096
    const unsigned short* vimg_b = vimg + (size_t)b * 524288;  // 64 tiles * 8192
    const f32x4 z4 = {0.f, 0.f, 0.f, 0.f};
    uint4 kr0, kr1, vr0, vr1, vr2, vr3;

#define KV_LOAD(s_) do {                                                            \
        const unsigned short* kp = &kimg_b[((size_t)(s_) * 2 + branch) * 4096];     \
        kr0 = *(const uint4*)&kp[tid8];                                             \
        kr1 = *(const uint4*)&kp[tid8 + 2048];                                      \
        const unsigned short* vp = &vimg_b[(size_t)(s_) * 8192];                    \
        vr0 = *(const uint4*)&vp[tid8];                                             \
        vr1 = *(const uint4*)&vp[tid8 + 2048];                                      \
        vr2 = *(const uint4*)&vp[tid8 + 4096];                                      \
        vr3 = *(const uint4*)&vp[tid8 + 6144];                                      \
    } while (0)

#define KV_STORE() do {                                                             \
        *(uint4*)&ksf[tid8] = kr0;                                                  \
        *(uint4*)&ksf[tid8 + 2048] = kr1;                                           \
        *(uint4*)&vtf[tid8] = vr0;                                                  \
        *(uint4*)&vtf[tid8 + 2048] = vr1;                                           \
        *(uint4*)&vtf[tid8 + 4096] = vr2;                                           \
        *(uint4*)&vtf[tid8 + 6144] = vr3;                                           \
    } while (0)

    #pragma unroll 1
    for (int seg = 0; seg < 2; ++seg) {
        const int t = seg ? (63 - bx) : bx;
        const int n = t + 1;
        const int s0 = (c * n) >> 2, smax = ((c + 1) * n) >> 2;

        float* rec = part + ((((size_t)b * 64 + t) * 4 + c) * 2 + branch) * REC_FLOATS;
        if (s0 >= smax) {  // empty chunk: zero this branch's record
            unsigned int* pz = (unsigned int*)rec;
            for (int i = tid; i < REC_FLOATS; i += 256) pz[i] = 0u;
            continue;
        }

        bf16x8 qf[2];
        for (int cc = 0; cc < 2; ++cc)
            qf[cc] = *(const bf16x8*)&q[(bbase + t * 64 + w * 16 + i16) * 128 + branch * 64 + cc * 32 + 8 * gq];

        float lsum = 0.f;
        f32x4 acc_o[8];
        for (int nb = 0; nb < 8; ++nb) acc_o[nb] = z4;

        KV_LOAD(s0);
        #pragma unroll 1
        for (int s = s0; s < smax; ++s) {
            __syncthreads();
            KV_STORE();
            if (s + 1 < smax) KV_LOAD(s + 1);
            __syncthreads();

            // S^T = mfma(K, Q): lane holds S[kv=cb*16+gq*4+r][q=w*16+i16]
            f32x4 sc[4];
            for (int cb = 0; cb < 4; ++cb) sc[cb] = z4;
            __builtin_amdgcn_s_setprio(1);
            #pragma unroll
            for (int cb = 0; cb < 4; ++cb)
                for (int cc = 0; cc < 2; ++cc) {
                    bf16x8 kf = *(const bf16x8*)&ksf[((cb * 2 + cc) * 64 + l) * 8];
                    sc[cb] = __builtin_amdgcn_mfma_f32_16x16x32_bf16(kf, qf[cc], sc[cb], 0, 0, 0);
                }
            __builtin_amdgcn_s_setprio(0);
            if (s == t) {  // causal mask on diagonal tile
                int ql = w * 16 + i16;
                for (int cb = 0; cb < 4; ++cb)
                    for (int r = 0; r < 4; ++r)
                        if (cb * 16 + gq * 4 + r > ql) sc[cb][r] = NEGINF;
            }
            // p = exp2(s*CEXP - MOFF); fixed max, per-lane lsum
            #pragma unroll
            for (int cb = 0; cb < 4; ++cb)
                for (int r = 0; r < 4; ++r) {
                    float pv = exp2f(fmaf(sc[cb][r], CEXP, -MOFF));
                    sc[cb][r] = pv;
                    lsum += pv;
                }
            // pack -> frag-linear P slots (b64 writes)
            #pragma unroll
            for (int cb = 0; cb < 4; ++cb) {
                uint2 pw;
                pw.x = cvt_pk_bf16(sc[cb][0], sc[cb][1]);
                pw.y = cvt_pk_bf16(sc[cb][2], sc[cb][3]);
                *(uint2*)&psf[pdst[cb]] = pw;
            }
            asm volatile("s_waitcnt lgkmcnt(0)" ::: "memory");  // wave-local
            bf16x8 pa0 = *(const bf16x8*)&psf[prd0];
            bf16x8 pa1 = *(const bf16x8*)&psf[prd1];
            __builtin_amdgcn_s_setprio(1);
            #pragma unroll
            for (int nb = 0; nb < 8; ++nb) {
                bf16x8 vb0 = *(const bf16x8*)&vtf[((nb * 2 + 0) * 64 + l) * 8];
                acc_o[nb] = __builtin_amdgcn_mfma_f32_16x16x32_bf16(pa0, vb0, acc_o[nb], 0, 0, 0);
                bf16x8 vb1 = *(const bf16x8*)&vtf[((nb * 2 + 1) * 64 + l) * 8];
                acc_o[nb] = __builtin_amdgcn_mfma_f32_16x16x32_bf16(pa1, vb1, acc_o[nb], 0, 0, 0);
            }
            __builtin_amdgcn_s_setprio(0);
        }

        // flush
        lsum += __shfl_xor(lsum, 16);
        lsum += __shfl_xor(lsum, 32);
        unsigned short* Orec = (unsigned short*)(rec + 64);
        if (gq == 0) rec[w * 16 + i16] = lsum;
        for (int nb = 0; nb < 8; ++nb)
            for (int r = 0; r < 4; ++r) {
                int row = w * 16 + gq * 4 + r;
                Orec[row * 128 + nb * 16 + i16] = f2bf(acc_o[nb][r]);
            }
    }
#undef KV_LOAD
#undef KV_STORE
}

// ---------------- combine: sum 4 chunks per branch, normalize, o1 - lam*o2 ----------------
__global__ __launch_bounds__(256) void diff_combine(
    const float* __restrict__ part,
    const float* __restrict__ lq1, const float* __restrict__ lq2,
    const float* __restrict__ lk1, const float* __restrict__ lk2,
    float* __restrict__ out) {
    const int t = blockIdx.x, b = blockIdx.y;
    const int tid = threadIdx.x;
    __shared__ float sl[2][64];
    __shared__ float s_lam;

    const float* recbase = part + (((size_t)b * 64 + t) * 4) * 2 * REC_FLOATS;

    if (tid < 64) {
        float s1 = lq1[tid] * lk1[tid];
        float s2 = lq2[tid] * lk2[tid];
        for (int off = 32; off > 0; off >>= 1) {
            s1 += __shfl_xor(s1, off);
            s2 += __shfl_xor(s2, off);
        }
        if (tid == 0) s_lam = expf(s1) - expf(s2) + LAMBDA_INIT;
    }
    if (tid < 128) {
        int r = tid & 63, br = tid >> 6;
        float acc = 0.f;
        for (int c = 0; c < 4; ++c) acc += recbase[(c * 2 + br) * REC_FLOATS + r];
        sl[br][r] = acc;
    }
    __syncthreads();
    const float lam = s_lam;

    float* op = out + ((size_t)b * 4096 + (size_t)t * 64) * 128;
    for (int grp = 0; grp < 4; ++grp) {
        int gid = grp * 256 + tid;
        int e = gid * 8;
        int row = e >> 7;
        float o1[8] = {0, 0, 0, 0, 0, 0, 0, 0}, o2[8] = {0, 0, 0, 0, 0, 0, 0, 0};
        #pragma unroll
        for (int c = 0; c < 4; ++c) {
            const unsigned short* O0 = (const unsigned short*)(recbase + (c * 2 + 0) * REC_FLOATS + 64);
            const unsigned short* O1 = (const unsigned short*)(recbase + (c * 2 + 1) * REC_FLOATS + 64);
            uint4 u0 = *(const uint4*)&O0[e];
            uint4 u1 = *(const uint4*)&O1[e];
            const unsigned short* e0 = (const unsigned short*)&u0;
            const unsigned short* e1 = (const unsigned short*)&u1;
            #pragma unroll
            for (int j = 0; j < 8; ++j) {
                o1[j] += bf2f(e0[j]);
                o2[j] += bf2f(e1[j]);
            }
        }
        float l1inv = 1.0f / sl[0][row], l2inv = 1.0f / sl[1][row];
        float res[8];
        #pragma unroll
        for (int j = 0; j < 8; ++j) res[j] = o1[j] * l1inv - lam * o2[j] * l2inv;
        *(float4*)&op[e] = *(float4*)&res[0];
        *(float4*)&op[e + 4] = *(float4*)&res[4];
    }
}

extern "C" void kernel_launch(void* const* d_in, const int* in_sizes, int n_in,
                              void* d_out, int out_size, void* d_ws, size_t ws_size,
                              hipStream_t stream) {
    const float* x   = (const float*)d_in[0];
    const float* Wq  = (const float*)d_in[1];
    const float* Wk  = (const float*)d_in[2];
    const float* Wv  = (const float*)d_in[3];
    const float* lq1 = (const float*)d_in[4];
    const float* lq2 = (const float*)d_in[5];
    const float* lk1 = (const float*)d_in[6];
    const float* lk2 = (const float*)d_in[7];
    float* out = (float*)d_out;
    unsigned short* qkv = (unsigned short*)d_ws;
    float* part = (float*)((char*)d_ws + PART_OFF_BYTES);
    unsigned short* WT = (unsigned short*)((char*)d_ws + WT_OFF_BYTES);

    prep_wt<<<dim3(16, 2, 3), 256, 0, stream>>>(Wq, Wk, Wv, WT);
    qkv_gemm<<<dim3(128, 3), 256, 0, stream>>>(x, WT, qkv);

    const unsigned short* qb = qkv;
    const unsigned short* kb = qkv + K_OFF;
    const unsigned short* vtb = qkv + VT_OFF;
    diff_attn_pair<<<dim3(32, 4, 8), 256, 0, stream>>>(qb, kb, vtb, part);
    diff_combine<<<dim3(64, 4), 256, 0, stream>>>(part, lq1, lq2, lk1, lk2, out);
}